// Round 3
// baseline (364.368 us; speedup 1.0000x reference)
//
#include <hip/hip_runtime.h>

// BilinearResNet fused forward, round 3.
// Round 2 post-mortem: per-lane row-strided float4 loads fetched 64 lines/instr
// with 16B used each; L1 (32KB) couldn't hold 56KB of wave working sets ->
// FETCH_SIZE 2x ideal (414MB), hbm 37% peak. Fix: stage x tile through LDS.
//   - loader: 64-row x 64-float chunks, 256B aligned contiguous runs per
//     16-lane group -> 16 fully-used lines per wave instr, no L1 reliance.
//   - double-buffered LDS (2 x 16KB), XOR swizzle kk^(row&15) so both
//     ds_write_b128 and ds_read_b128 hit the b128 throughput floor.
//   - compute: round-2 wave-uniform K-split (scalar weight loads) from LDS.
// 1024 blocks x 256 threads = 16 waves/CU.

#define IN_DIM   784
#define D_MODEL  16
#define HIDDEN   6
#define N_BLOCKS 4
#define N_CLS    10
#define BATCH    65536
#define NCHUNK   12        // 12 x 64 floats + 16-float tail

__global__ __launch_bounds__(256, 4) void bilinear_resnet_fused(
    const float* __restrict__ x,
    const float* __restrict__ W_embed,   // [16][784]
    const float* __restrict__ L_w,       // [4][6][16]
    const float* __restrict__ R_w,       // [4][6][16]
    const float* __restrict__ D_w,       // [4][16][6]
    const float* __restrict__ W_head,    // [10][16]
    float* __restrict__ out)
{
    __shared__ float4 buf[2][64 * 16];   // 2 x 16 KB

    const int tid  = threadIdx.x;
    const int lane = tid & 63;
    const int wv   = __builtin_amdgcn_readfirstlane(tid >> 6);  // 0..3, uniform
    const int row  = blockIdx.x * 64 + lane;

    const float* xtile = x + (size_t)blockIdx.x * 64 * IN_DIM;

    float acc[D_MODEL];
#pragma unroll
    for (int d = 0; d < D_MODEL; ++d) acc[d] = 0.f;

    // loader-role indices: f4 slot i = it*256 + tid -> row r=i>>4, col kk=i&15
    int lr[4], lk[4];
#pragma unroll
    for (int it = 0; it < 4; ++it) {
        int i = it * 256 + tid;
        lr[it] = i >> 4;
        lk[it] = i & 15;
    }

    // ---- prefetch + stage chunk 0 ----
    float4 pf[4];
#pragma unroll
    for (int it = 0; it < 4; ++it)
        pf[it] = *reinterpret_cast<const float4*>(
            xtile + (size_t)lr[it] * IN_DIM + lk[it] * 4);
#pragma unroll
    for (int it = 0; it < 4; ++it)
        buf[0][lr[it] * 16 + (lk[it] ^ (lr[it] & 15))] = pf[it];
    __syncthreads();

    // ---- main K loop, double-buffered ----
    for (int c = 0; c < NCHUNK; ++c) {
        if (c + 1 < NCHUNK) {
#pragma unroll
            for (int it = 0; it < 4; ++it)
                pf[it] = *reinterpret_cast<const float4*>(
                    xtile + (size_t)lr[it] * IN_DIM + (c + 1) * 64 + lk[it] * 4);
        }
        // compute chunk c: lane = row, columns c*64 + wv*16 + [0..16)
        const float* wc = W_embed + c * 64 + wv * 16;   // uniform
        const float4* bsrc = buf[c & 1];
#pragma unroll
        for (int j = 0; j < 4; ++j) {
            const int kk = wv * 4 + j;
            const float4 xv = bsrc[lane * 16 + (kk ^ (lane & 15))];
#pragma unroll
            for (int d = 0; d < D_MODEL; ++d) {
                const float* wd = wc + d * IN_DIM + j * 4;  // uniform -> s_load
                float s = acc[d];
                s = fmaf(xv.x, wd[0], s);
                s = fmaf(xv.y, wd[1], s);
                s = fmaf(xv.z, wd[2], s);
                s = fmaf(xv.w, wd[3], s);
                acc[d] = s;
            }
        }
        if (c + 1 < NCHUNK) {
#pragma unroll
            for (int it = 0; it < 4; ++it)
                buf[(c + 1) & 1][lr[it] * 16 + (lk[it] ^ (lr[it] & 15))] = pf[it];
        }
        __syncthreads();
    }

    // ---- tail: columns 768..784, 4 floats per wave, direct global ----
    {
        const float4 xv = *reinterpret_cast<const float4*>(
            x + (size_t)row * IN_DIM + 768 + wv * 4);
        const float* wt = W_embed + 768 + wv * 4;   // uniform
#pragma unroll
        for (int d = 0; d < D_MODEL; ++d) {
            const float* wd = wt + d * IN_DIM;
            float s = acc[d];
            s = fmaf(xv.x, wd[0], s);
            s = fmaf(xv.y, wd[1], s);
            s = fmaf(xv.z, wd[2], s);
            s = fmaf(xv.w, wd[3], s);
            acc[d] = s;
        }
    }

    // ---- reduce 4 wave-partials per row (reuse buf[0] region, stride 17) ----
    float* parts = reinterpret_cast<float*>(&buf[0][0]);
    if (wv != 0) {
#pragma unroll
        for (int d = 0; d < D_MODEL; ++d)
            parts[((wv - 1) * 64 + lane) * 17 + d] = acc[d];
    }
    __syncthreads();
    if (wv != 0) return;

#pragma unroll
    for (int d = 0; d < D_MODEL; ++d)
        acc[d] += parts[(0 * 64 + lane) * 17 + d]
                + parts[(1 * 64 + lane) * 17 + d]
                + parts[(2 * 64 + lane) * 17 + d];

    // ---- bilinear residual blocks (wave 0; uniform weights -> scalar) ----
#pragma unroll
    for (int b = 0; b < N_BLOCKS; ++b) {
        const float* Lb = L_w + b * HIDDEN * D_MODEL;
        const float* Rb = R_w + b * HIDDEN * D_MODEL;
        const float* Db = D_w + b * D_MODEL * HIDDEN;
        float h[HIDDEN];
#pragma unroll
        for (int j = 0; j < HIDDEN; ++j) {
            float u = 0.f, v = 0.f;
#pragma unroll
            for (int d = 0; d < D_MODEL; ++d) {
                u = fmaf(acc[d], Lb[j * D_MODEL + d], u);
                v = fmaf(acc[d], Rb[j * D_MODEL + d], v);
            }
            h[j] = u * v;
        }
#pragma unroll
        for (int d = 0; d < D_MODEL; ++d) {
            float s = acc[d];
#pragma unroll
            for (int j = 0; j < HIDDEN; ++j) s = fmaf(h[j], Db[d * HIDDEN + j], s);
            acc[d] = s;
        }
        float* hout = out + (size_t)N_CLS * BATCH + (size_t)b * HIDDEN * BATCH
                      + (size_t)row * HIDDEN;
#pragma unroll
        for (int j = 0; j < HIDDEN; ++j) hout[j] = h[j];
    }

    // ---- head ----
    float* lout = out + (size_t)row * N_CLS;
#pragma unroll
    for (int k = 0; k < N_CLS; ++k) {
        float s = 0.f;
#pragma unroll
        for (int d = 0; d < D_MODEL; ++d) s = fmaf(acc[d], W_head[k * D_MODEL + d], s);
        lout[k] = s;
    }
}

extern "C" void kernel_launch(void* const* d_in, const int* in_sizes, int n_in,
                              void* d_out, int out_size, void* d_ws, size_t ws_size,
                              hipStream_t stream) {
    const float* x       = (const float*)d_in[0];
    const float* W_embed = (const float*)d_in[1];
    const float* L_w     = (const float*)d_in[2];
    const float* R_w     = (const float*)d_in[3];
    const float* D_w     = (const float*)d_in[4];
    const float* W_head  = (const float*)d_in[5];
    float* out = (float*)d_out;

    const int grid = BATCH / 64;   // 1024 blocks, 64 rows each
    bilinear_resnet_fused<<<grid, 256, 0, stream>>>(
        x, W_embed, L_w, R_w, D_w, W_head, out);
}

// Round 4
// 335.089 us; speedup vs baseline: 1.0874x; 1.0874x over previous
//
#include <hip/hip_runtime.h>

// BilinearResNet fused forward, round 4.
// Round 3 post-mortem: the pf[4] double-buffer register array was demoted to
// scratch -> 204 MB of HBM write traffic (16KB/chunk x 12 x 1024 blocks), the
// exact staged byte count. Fix: async global->LDS DMA via
// __builtin_amdgcn_global_load_lds width=16 -- no VGPR/scratch round trip.
// LDS dest is wave-uniform base + lane*16, so the XOR swizzle is applied on
// the SOURCE side: slot s holds x[r=s>>4][kk=(s&15)^(r&15)]. Each 16-lane
// group then reads a permutation within one 256B-aligned run (coalescing
// preserved), and the compute read pattern is identical to round 3's
// measured 0-conflict layout.
// 1024 blocks x 256 threads = 16 waves/CU; m97-style 2-barrier K-loop.

#define IN_DIM   784
#define D_MODEL  16
#define HIDDEN   6
#define N_BLOCKS 4
#define N_CLS    10
#define BATCH    65536
#define NCHUNK   12        // 12 x 64-float chunks + 16-float tail

typedef const __attribute__((address_space(1))) void gvoid_t;
typedef __attribute__((address_space(3))) void svoid_t;

__global__ __launch_bounds__(256, 4) void bilinear_resnet_fused(
    const float* __restrict__ x,
    const float* __restrict__ W_embed,   // [16][784]
    const float* __restrict__ L_w,       // [4][6][16]
    const float* __restrict__ R_w,       // [4][6][16]
    const float* __restrict__ D_w,       // [4][16][6]
    const float* __restrict__ W_head,    // [10][16]
    float* __restrict__ out)
{
    __shared__ float4 buf[2][64 * 16];   // 2 x 16 KB

    const int tid  = threadIdx.x;
    const int lane = tid & 63;
    const int wv   = __builtin_amdgcn_readfirstlane(tid >> 6);  // 0..3 uniform
    const int row  = blockIdx.x * 64 + lane;
    const float* xtile = x + (size_t)blockIdx.x * 64 * IN_DIM;

    // stage decode, chunk-invariant: for (it, wv), lane l covers LDS slot
    // s = it*256 + wv*64 + l  ->  r = it*16 + wv*4 + (l>>4),
    // stored kk = (l&15) ^ (r&15), with r&15 = wv*4 + (l>>4).
    const int sub   = lane >> 4;
    const int rmod  = wv * 4 + sub;          // r & 15
    const int kk_l  = (lane & 15) ^ rmod;    // source column group (x4 floats)

    float acc[D_MODEL];
#pragma unroll
    for (int d = 0; d < D_MODEL; ++d) acc[d] = 0.f;

    // ---- async-stage chunk 0 ----
#pragma unroll
    for (int it = 0; it < 4; ++it) {
        const int r = it * 16 + rmod;
        const float* g = xtile + (size_t)r * IN_DIM + kk_l * 4;
        char* l = (char*)(&buf[0][0]) + (it * 256 + wv * 64) * 16;
        __builtin_amdgcn_global_load_lds((gvoid_t*)g, (svoid_t*)l, 16, 0, 0);
    }
    __syncthreads();

    // ---- main K loop, double-buffered (m97 2-barrier structure) ----
    for (int c = 0; c < NCHUNK; ++c) {
        if (c + 1 < NCHUNK) {
#pragma unroll
            for (int it = 0; it < 4; ++it) {
                const int r = it * 16 + rmod;
                const float* g = xtile + (size_t)r * IN_DIM + (c + 1) * 64 + kk_l * 4;
                char* l = (char*)(&buf[(c + 1) & 1][0]) + (it * 256 + wv * 64) * 16;
                __builtin_amdgcn_global_load_lds((gvoid_t*)g, (svoid_t*)l, 16, 0, 0);
            }
        }
        // compute chunk c: lane = row, wave handles kk = wv*4 + [0..4)
        const float* wc = W_embed + c * 64 + wv * 16;   // uniform
        const float4* bsrc = buf[c & 1];
#pragma unroll
        for (int j = 0; j < 4; ++j) {
            const int kk = wv * 4 + j;
            const float4 xv = bsrc[lane * 16 + (kk ^ (lane & 15))];
#pragma unroll
            for (int d = 0; d < D_MODEL; ++d) {
                const float* wd = wc + d * IN_DIM + j * 4;  // uniform -> s_load
                float s = acc[d];
                s = fmaf(xv.x, wd[0], s);
                s = fmaf(xv.y, wd[1], s);
                s = fmaf(xv.z, wd[2], s);
                s = fmaf(xv.w, wd[3], s);
                acc[d] = s;
            }
        }
        __syncthreads();   // drains vmcnt (prefetch done) + barrier
    }

    // ---- tail: columns 768..784 (one 64B line per row), direct global ----
    {
        const float4 xv = *reinterpret_cast<const float4*>(
            x + (size_t)row * IN_DIM + 768 + wv * 4);
        const float* wt = W_embed + 768 + wv * 4;   // uniform
#pragma unroll
        for (int d = 0; d < D_MODEL; ++d) {
            const float* wd = wt + d * IN_DIM;
            float s = acc[d];
            s = fmaf(xv.x, wd[0], s);
            s = fmaf(xv.y, wd[1], s);
            s = fmaf(xv.z, wd[2], s);
            s = fmaf(xv.w, wd[3], s);
            acc[d] = s;
        }
    }

    // ---- reduce 4 wave-partials per row (reuse buf[0], stride 17) ----
    float* parts = reinterpret_cast<float*>(&buf[0][0]);
    if (wv != 0) {
#pragma unroll
        for (int d = 0; d < D_MODEL; ++d)
            parts[((wv - 1) * 64 + lane) * 17 + d] = acc[d];
    }
    __syncthreads();
    if (wv != 0) return;

#pragma unroll
    for (int d = 0; d < D_MODEL; ++d)
        acc[d] += parts[(0 * 64 + lane) * 17 + d]
                + parts[(1 * 64 + lane) * 17 + d]
                + parts[(2 * 64 + lane) * 17 + d];

    // ---- bilinear residual blocks (wave 0; uniform weights -> scalar) ----
#pragma unroll
    for (int b = 0; b < N_BLOCKS; ++b) {
        const float* Lb = L_w + b * HIDDEN * D_MODEL;
        const float* Rb = R_w + b * HIDDEN * D_MODEL;
        const float* Db = D_w + b * D_MODEL * HIDDEN;
        float h[HIDDEN];
#pragma unroll
        for (int j = 0; j < HIDDEN; ++j) {
            float u = 0.f, v = 0.f;
#pragma unroll
            for (int d = 0; d < D_MODEL; ++d) {
                u = fmaf(acc[d], Lb[j * D_MODEL + d], u);
                v = fmaf(acc[d], Rb[j * D_MODEL + d], v);
            }
            h[j] = u * v;
        }
#pragma unroll
        for (int d = 0; d < D_MODEL; ++d) {
            float s = acc[d];
#pragma unroll
            for (int j = 0; j < HIDDEN; ++j) s = fmaf(h[j], Db[d * HIDDEN + j], s);
            acc[d] = s;
        }
        float* hout = out + (size_t)N_CLS * BATCH + (size_t)b * HIDDEN * BATCH
                      + (size_t)row * HIDDEN;
#pragma unroll
        for (int j = 0; j < HIDDEN; ++j) hout[j] = h[j];
    }

    // ---- head ----
    float* lout = out + (size_t)row * N_CLS;
#pragma unroll
    for (int k = 0; k < N_CLS; ++k) {
        float s = 0.f;
#pragma unroll
        for (int d = 0; d < D_MODEL; ++d) s = fmaf(acc[d], W_head[k * D_MODEL + d], s);
        lout[k] = s;
    }
}

extern "C" void kernel_launch(void* const* d_in, const int* in_sizes, int n_in,
                              void* d_out, int out_size, void* d_ws, size_t ws_size,
                              hipStream_t stream) {
    const float* x       = (const float*)d_in[0];
    const float* W_embed = (const float*)d_in[1];
    const float* L_w     = (const float*)d_in[2];
    const float* R_w     = (const float*)d_in[3];
    const float* D_w     = (const float*)d_in[4];
    const float* W_head  = (const float*)d_in[5];
    float* out = (float*)d_out;

    const int grid = BATCH / 64;   // 1024 blocks, 64 rows each
    bilinear_resnet_fused<<<grid, 256, 0, stream>>>(
        x, W_embed, L_w, R_w, D_w, W_head, out);
}